// Round 4
// baseline (2940.560 us; speedup 1.0000x reference)
//
#include <hip/hip_runtime.h>
#include <stdint.h>

#define Bq    2048
#define NNq   24
#define NCq   8
#define CARDq 16
#define Dq    512
#define Hq    8
#define Lq    3
#define FHq   1024
#define Sq    33

typedef unsigned short u16;
typedef unsigned int   u32;
typedef __bf16 bf16x8 __attribute__((ext_vector_type(8)));
typedef float  f32x4  __attribute__((ext_vector_type(4)));

__device__ __forceinline__ u16 f2bf(float f) {
  u32 u = __builtin_bit_cast(u32, f);
  u = (u + 0x7fffu + ((u >> 16) & 1u)) >> 16;
  return (u16)u;
}
__device__ __forceinline__ float bf2f(u16 h) {
  u32 u = ((u32)h) << 16;
  return __builtin_bit_cast(float, u);
}

__device__ __forceinline__ void glds16(const void* g, void* l) {
  __builtin_amdgcn_global_load_lds((const __attribute__((address_space(1))) void*)g,
                                   (__attribute__((address_space(3))) void*)l, 16, 0, 0);
}

// ---------------- weight transpose + f32->bf16 : src [L][K][N] -> dst [L][N][K]
__global__ __launch_bounds__(256) void wconv_kernel(const float* __restrict__ src,
                                                    u16* __restrict__ dst, int K, int N) {
  __shared__ float tile[32][33];
  const int l = blockIdx.z;
  src += (size_t)l * K * N;
  dst += (size_t)l * K * N;
  const int n0 = blockIdx.x * 32, k0 = blockIdx.y * 32;
  const int tx = threadIdx.x & 31, ty = threadIdx.x >> 5;
#pragma unroll
  for (int r = 0; r < 32; r += 8)
    tile[ty + r][tx] = src[(size_t)(k0 + ty + r) * N + (n0 + tx)];
  __syncthreads();
#pragma unroll
  for (int r = 0; r < 32; r += 8)
    dst[(size_t)(n0 + ty + r) * K + (k0 + tx)] = f2bf(tile[tx][ty + r]);
}

// ---------------- fused tokenizer + LN1(layer0): one wave per token
// writes X fp32 [Mc,512] and H = LN(X) bf16 [Mc,512]
__global__ __launch_bounds__(256) void tok_ln_kernel(const float* __restrict__ x_num,
                                                     const int* __restrict__ x_cat,
                                                     const float* __restrict__ w_num,
                                                     const float* __restrict__ b_num,
                                                     const float* __restrict__ emb_cat,
                                                     const float* __restrict__ b_cat,
                                                     const float* __restrict__ cls,
                                                     const float* __restrict__ gw,
                                                     const float* __restrict__ gb,
                                                     float* __restrict__ X,
                                                     u16* __restrict__ Hout, int c0) {
  const int wave = threadIdx.x >> 6, lane = threadIdx.x & 63;
  const int tok = blockIdx.x * 4 + wave;
  const int b   = tok / Sq;
  const int s   = tok - b * Sq;
  const int bg  = c0 + b;
  const int col0 = lane * 8;
  float v[8];
  if (s < NNq) {
    const float xv = x_num[bg * NNq + s];
    const float4 w0 = *(const float4*)(w_num + s * Dq + col0);
    const float4 w1 = *(const float4*)(w_num + s * Dq + col0 + 4);
    const float4 b0 = *(const float4*)(b_num + s * Dq + col0);
    const float4 b1 = *(const float4*)(b_num + s * Dq + col0 + 4);
    v[0]=fmaf(xv,w0.x,b0.x); v[1]=fmaf(xv,w0.y,b0.y); v[2]=fmaf(xv,w0.z,b0.z); v[3]=fmaf(xv,w0.w,b0.w);
    v[4]=fmaf(xv,w1.x,b1.x); v[5]=fmaf(xv,w1.y,b1.y); v[6]=fmaf(xv,w1.z,b1.z); v[7]=fmaf(xv,w1.w,b1.w);
  } else if (s < NNq + NCq) {
    const int j = s - NNq;
    const int row = x_cat[bg * NCq + j] + j * CARDq;
    const float4 e0 = *(const float4*)(emb_cat + (size_t)row * Dq + col0);
    const float4 e1 = *(const float4*)(emb_cat + (size_t)row * Dq + col0 + 4);
    const float4 b0 = *(const float4*)(b_cat + j * Dq + col0);
    const float4 b1 = *(const float4*)(b_cat + j * Dq + col0 + 4);
    v[0]=e0.x+b0.x; v[1]=e0.y+b0.y; v[2]=e0.z+b0.z; v[3]=e0.w+b0.w;
    v[4]=e1.x+b1.x; v[5]=e1.y+b1.y; v[6]=e1.z+b1.z; v[7]=e1.w+b1.w;
  } else {
    const float4 c0v = *(const float4*)(cls + col0);
    const float4 c1v = *(const float4*)(cls + col0 + 4);
    v[0]=c0v.x; v[1]=c0v.y; v[2]=c0v.z; v[3]=c0v.w;
    v[4]=c1v.x; v[5]=c1v.y; v[6]=c1v.z; v[7]=c1v.w;
  }
  float s1 = 0.f, s2 = 0.f;
#pragma unroll
  for (int i = 0; i < 8; i++) { s1 += v[i]; s2 += v[i] * v[i]; }
#pragma unroll
  for (int off = 32; off > 0; off >>= 1) { s1 += __shfl_xor(s1, off); s2 += __shfl_xor(s2, off); }
  const float mean = s1 * (1.0f / Dq);
  const float rstd = rsqrtf(s2 * (1.0f / Dq) - mean * mean + 1e-5f);
  float* xp = X + (size_t)tok * Dq + col0;
  *(float4*)xp       = (float4){v[0], v[1], v[2], v[3]};
  *(float4*)(xp + 4) = (float4){v[4], v[5], v[6], v[7]};
  const float* gwp = gw + col0;
  const float* gbp = gb + col0;
  u16 o[8];
#pragma unroll
  for (int i = 0; i < 8; i++) o[i] = f2bf((v[i] - mean) * rstd * gwp[i] + gbp[i]);
  uint4 pk;
  pk.x = (u32)o[0] | ((u32)o[1] << 16); pk.y = (u32)o[2] | ((u32)o[3] << 16);
  pk.z = (u32)o[4] | ((u32)o[5] << 16); pk.w = (u32)o[6] | ((u32)o[7] << 16);
  *(uint4*)(Hout + (size_t)tok * Dq + col0) = pk;
}

// ---------------- GEMM: C[M,N] = A[M,K] @ Bt[N,K]^T (+bias, mode-specific epilogue)
// MODE 0: out = bf16(acc + bias)           (QKV; z selects B/bias/out)
// MODE 1: X fp32 += acc + bias             (plain residual, last FFN2)
// MODE 2: AG = bf16((acc_a+ba)*relu(acc_g+bg))  (fused ReGLU FFN1)
template <int MODE>
__global__ __launch_bounds__(256) void gemm_kernel(const u16* __restrict__ A,
                                                   const u16* __restrict__ Bt0, const u16* __restrict__ Bt1, const u16* __restrict__ Bt2,
                                                   const float* __restrict__ bi0, const float* __restrict__ bi1, const float* __restrict__ bi2,
                                                   void* __restrict__ out0, void* __restrict__ out1, void* __restrict__ out2,
                                                   int K) {
  __shared__ uint4 smem4[1024];   // 16 KB
  char* smem = (char*)smem4;
  const int tid  = threadIdx.x;
  const int wave = tid >> 6;
  const int lane = tid & 63;
  const int mblk = blockIdx.x;
  const int nblk = blockIdx.y;
  const int z    = blockIdx.z;
  const u16*   Bt   = (z == 0) ? Bt0 : (z == 1) ? Bt1 : Bt2;
  const float* bias = (z == 0) ? bi0 : (z == 1) ? bi1 : bi2;
  void*        outp = (z == 0) ? out0 : (z == 1) ? out1 : out2;

  const int cg   = (lane & 3) ^ ((lane >> 3) & 3);
  const int arow = wave * 32 + (lane >> 2);
  const u16* gA0 = A + (size_t)(mblk * 128 + arow) * K + cg * 8;
  const u16* gA1 = gA0 + (size_t)16 * K;
  char* lA0 = smem + wave * 2048;
  char* lA1 = lA0 + 1024;

  const u16 *gB0, *gB1;
  char *lB0, *lB1;
  if (MODE == 2) {
    const int brow = wave * 16 + (lane >> 2);
    gB0 = Bt + (size_t)(nblk * 64 + brow) * K + cg * 8;
    gB1 = Bt + (size_t)(FHq + nblk * 64 + brow) * K + cg * 8;
    lB0 = smem + 8192  + wave * 1024;
    lB1 = smem + 12288 + wave * 1024;
  } else {
    const int brow = wave * 32 + (lane >> 2);
    gB0 = Bt + (size_t)(nblk * 128 + brow) * K + cg * 8;
    gB1 = gB0 + (size_t)16 * K;
    lB0 = smem + 8192 + wave * 2048;
    lB1 = lB0 + 1024;
  }

  const int slot = (lane >> 4) ^ ((lane >> 1) & 3);
  const int r16  = lane & 15;
  const int wm   = (wave >> 1) * 64;
  int aoff[4], boff[4];
#pragma unroll
  for (int i = 0; i < 4; i++) aoff[i] = (wm + i * 16 + r16) * 64 + slot * 16;
  if (MODE == 2) {
    const int wn = (wave & 1) * 32;
#pragma unroll
    for (int j = 0; j < 2; j++) {
      boff[j]     = 8192  + (wn + j * 16 + r16) * 64 + slot * 16;
      boff[2 + j] = 12288 + (wn + j * 16 + r16) * 64 + slot * 16;
    }
  } else {
    const int wn = (wave & 1) * 64;
#pragma unroll
    for (int j = 0; j < 4; j++) boff[j] = 8192 + (wn + j * 16 + r16) * 64 + slot * 16;
  }

  f32x4 acc[16];
#pragma unroll
  for (int i = 0; i < 16; i++) acc[i] = (f32x4){0.f, 0.f, 0.f, 0.f};

  const int kiter = K >> 5;
  for (int kk = 0; kk < kiter; kk++) {
    __syncthreads();
    glds16(gA0, lA0); glds16(gA1, lA1);
    glds16(gB0, lB0); glds16(gB1, lB1);
    gA0 += 32; gA1 += 32; gB0 += 32; gB1 += 32;
    __syncthreads();

    if (MODE == 2) {
      bf16x8 af[4], ba[2], bg[2];
#pragma unroll
      for (int i = 0; i < 4; i++) af[i] = *(const bf16x8*)(smem + aoff[i]);
#pragma unroll
      for (int j = 0; j < 2; j++) {
        ba[j] = *(const bf16x8*)(smem + boff[j]);
        bg[j] = *(const bf16x8*)(smem + boff[2 + j]);
      }
#pragma unroll
      for (int i = 0; i < 4; i++)
#pragma unroll
        for (int j = 0; j < 2; j++) {
          acc[i * 2 + j]     = __builtin_amdgcn_mfma_f32_16x16x32_bf16(af[i], ba[j], acc[i * 2 + j], 0, 0, 0);
          acc[8 + i * 2 + j] = __builtin_amdgcn_mfma_f32_16x16x32_bf16(af[i], bg[j], acc[8 + i * 2 + j], 0, 0, 0);
        }
    } else {
      bf16x8 af[4], bf[4];
#pragma unroll
      for (int i = 0; i < 4; i++) af[i] = *(const bf16x8*)(smem + aoff[i]);
#pragma unroll
      for (int j = 0; j < 4; j++) bf[j] = *(const bf16x8*)(smem + boff[j]);
#pragma unroll
      for (int i = 0; i < 4; i++)
#pragma unroll
        for (int j = 0; j < 4; j++)
          acc[i * 4 + j] = __builtin_amdgcn_mfma_f32_16x16x32_bf16(af[i], bf[j], acc[i * 4 + j], 0, 0, 0);
    }
  }

  const int quad = lane >> 4;
  if (MODE == 0) {
    u16* C = (u16*)outp;
    const int wn = (wave & 1) * 64;
#pragma unroll
    for (int j = 0; j < 4; j++) {
      const int c = nblk * 128 + wn + j * 16 + r16;
      const float bv = bias[c];
#pragma unroll
      for (int i = 0; i < 4; i++) {
        const int r0 = mblk * 128 + wm + i * 16 + quad * 4;
        f32x4 v = acc[i * 4 + j];
#pragma unroll
        for (int r = 0; r < 4; r++)
          C[(size_t)(r0 + r) * Dq + c] = f2bf(v[r] + bv);
      }
    }
  } else if (MODE == 1) {
    float* X = (float*)outp;
    const int wn = (wave & 1) * 64;
#pragma unroll
    for (int j = 0; j < 4; j++) {
      const int c = nblk * 128 + wn + j * 16 + r16;
      const float bv = bias[c];
#pragma unroll
      for (int i = 0; i < 4; i++) {
        const int r0 = mblk * 128 + wm + i * 16 + quad * 4;
        f32x4 v = acc[i * 4 + j];
#pragma unroll
        for (int r = 0; r < 4; r++) {
          const size_t idx = (size_t)(r0 + r) * Dq + c;
          X[idx] += v[r] + bv;
        }
      }
    }
  } else {
    u16* AG = (u16*)outp;
    const int wn = (wave & 1) * 32;
#pragma unroll
    for (int j = 0; j < 2; j++) {
      const int c = nblk * 64 + wn + j * 16 + r16;
      const float bva = bias[c];
      const float bvg = bias[FHq + c];
#pragma unroll
      for (int i = 0; i < 4; i++) {
        const int r0 = mblk * 128 + wm + i * 16 + quad * 4;
        f32x4 va = acc[i * 2 + j];
        f32x4 vg = acc[8 + i * 2 + j];
#pragma unroll
        for (int r = 0; r < 4; r++) {
          const float av = va[r] + bva;
          const float gv = vg[r] + bvg;
          AG[(size_t)(r0 + r) * FHq + c] = f2bf(av * fmaxf(gv, 0.f));
        }
      }
    }
  }
}

// ---------------- fused GEMM + residual + LayerNorm (N = 512 = full row)
// BM=64, BN=512, BK=32, 512 threads (8 waves, each 32 rows x 128 cols).
// X fp32 += acc + bias; H = bf16(LN(Xnew)) with (gw, gb).
// In-place A->H is safe: each block reads only its own 64 A rows.
__global__ __launch_bounds__(512, 2) void gemm_ln_kernel(const u16* __restrict__ A,
                                                         const u16* __restrict__ Bt,
                                                         const float* __restrict__ bias,
                                                         const float* __restrict__ gw,
                                                         const float* __restrict__ gb,
                                                         float* __restrict__ X,
                                                         u16* __restrict__ Hout,
                                                         int K) {
  __shared__ uint4 smem4[2432];   // 4KB A + 32KB B + 2KB stats + pad = 38912 B
  char* smem = (char*)smem4;
  float* stats = (float*)(smem + 36864);   // [4 wn][64 rows][2]
  const int tid  = threadIdx.x;
  const int wave = tid >> 6;
  const int lane = tid & 63;
  const int mblk = blockIdx.x;

  // staging: 36 segments of 1KB (16 rows x 64B); wave w does s = w, w+8, ...
  const int nseg = (wave < 4) ? 5 : 4;
  const u16* gseg[5];
  char* lseg[5];
  {
    const int rloc = lane >> 2;
    const int cg   = (lane & 3) ^ ((lane >> 3) & 3);
#pragma unroll
    for (int t = 0; t < 5; t++) {
      const int s = wave + 8 * t;
      if (t < nseg) {
        if (s < 4) {
          gseg[t] = A + (size_t)(mblk * 64 + s * 16 + rloc) * K + cg * 8;
          lseg[t] = smem + s * 1024;
        } else {
          gseg[t] = Bt + (size_t)((s - 4) * 16 + rloc) * K + cg * 8;
          lseg[t] = smem + 4096 + (s - 4) * 1024;
        }
      }
    }
  }

  const int slot = (lane >> 4) ^ ((lane >> 1) & 3);
  const int r16  = lane & 15;
  const int quad = lane >> 4;
  const int wmo  = (wave >> 2) * 32;     // 0 or 32 (row half)
  const int wno  = (wave & 3) * 128;     // col group
  int aoff[2], boff[8];
#pragma unroll
  for (int i = 0; i < 2; i++) aoff[i] = (wmo + i * 16 + r16) * 64 + slot * 16;
#pragma unroll
  for (int j = 0; j < 8; j++) boff[j] = 4096 + (wno + j * 16 + r16) * 64 + slot * 16;

  f32x4 acc[16];
#pragma unroll
  for (int i = 0; i < 16; i++) acc[i] = (f32x4){0.f, 0.f, 0.f, 0.f};

  const int kiter = K >> 5;
  for (int kk = 0; kk < kiter; kk++) {
    __syncthreads();
    for (int t = 0; t < nseg; t++) { glds16(gseg[t], lseg[t]); gseg[t] += 32; }
    __syncthreads();
    bf16x8 af[2], bf[8];
#pragma unroll
    for (int i = 0; i < 2; i++) af[i] = *(const bf16x8*)(smem + aoff[i]);
#pragma unroll
    for (int j = 0; j < 8; j++) bf[j] = *(const bf16x8*)(smem + boff[j]);
#pragma unroll
    for (int i = 0; i < 2; i++)
#pragma unroll
      for (int j = 0; j < 8; j++)
        acc[i * 8 + j] = __builtin_amdgcn_mfma_f32_16x16x32_bf16(af[i], bf[j], acc[i * 8 + j], 0, 0, 0);
  }

  // ---- epilogue: residual add -> X, row stats -> LDS, LN -> H
  float bv[8];
#pragma unroll
  for (int j = 0; j < 8; j++) bv[j] = bias[wno + j * 16 + r16];

#pragma unroll
  for (int i = 0; i < 2; i++) {
#pragma unroll
    for (int r = 0; r < 4; r++) {
      const int row = mblk * 64 + wmo + i * 16 + quad * 4 + r;
#pragma unroll
      for (int j = 0; j < 8; j++) {
        const size_t idx = (size_t)row * Dq + wno + j * 16 + r16;
        const float xv = X[idx] + acc[i * 8 + j][r] + bv[j];
        acc[i * 8 + j][r] = xv;
        X[idx] = xv;
      }
    }
  }
  // partial sums over this wave's 128 cols
#pragma unroll
  for (int i = 0; i < 2; i++) {
#pragma unroll
    for (int r = 0; r < 4; r++) {
      float ps = 0.f, pq = 0.f;
#pragma unroll
      for (int j = 0; j < 8; j++) { const float xv = acc[i * 8 + j][r]; ps += xv; pq += xv * xv; }
#pragma unroll
      for (int off = 8; off > 0; off >>= 1) { ps += __shfl_xor(ps, off); pq += __shfl_xor(pq, off); }
      if (r16 == 0) {
        const int rloc = wmo + i * 16 + quad * 4 + r;
        stats[((wave & 3) * 64 + rloc) * 2 + 0] = ps;
        stats[((wave & 3) * 64 + rloc) * 2 + 1] = pq;
      }
    }
  }
  __syncthreads();

  float gwv[8], gbv[8];
#pragma unroll
  for (int j = 0; j < 8; j++) { gwv[j] = gw[wno + j * 16 + r16]; gbv[j] = gb[wno + j * 16 + r16]; }

#pragma unroll
  for (int i = 0; i < 2; i++) {
#pragma unroll
    for (int r = 0; r < 4; r++) {
      const int rloc = wmo + i * 16 + quad * 4 + r;
      float s1 = 0.f, s2 = 0.f;
#pragma unroll
      for (int w = 0; w < 4; w++) { s1 += stats[(w * 64 + rloc) * 2 + 0]; s2 += stats[(w * 64 + rloc) * 2 + 1]; }
      const float mean = s1 * (1.0f / Dq);
      const float rstd = rsqrtf(s2 * (1.0f / Dq) - mean * mean + 1e-5f);
      const int row = mblk * 64 + rloc;
#pragma unroll
      for (int j = 0; j < 8; j++) {
        const float h = (acc[i * 8 + j][r] - mean) * rstd * gwv[j] + gbv[j];
        Hout[(size_t)row * Dq + wno + j * 16 + r16] = f2bf(h);
      }
    }
  }
}

// ---------------- MFMA sparse attention: 4 waves/block, 1 head per wave
__global__ __launch_bounds__(256) void attn_mfma_kernel(const u16* __restrict__ Q,
                                                        const u16* __restrict__ K,
                                                        const u16* __restrict__ V,
                                                        const void* __restrict__ maskp,
                                                        int l, u16* __restrict__ O) {
  __shared__ u16 lds_all[4][8064];
  const int wave = threadIdx.x >> 6, lane = threadIdx.x & 63;
  const int b = blockIdx.x >> 1;
  const int h = (blockIdx.x & 1) * 4 + wave;
  u16* VT = &lds_all[wave][0];
  u16* P  = &lds_all[wave][64 * 72];
  const size_t hbase = (size_t)b * (Sq * Dq) + (size_t)h * 64;
  const int r16 = lane & 15, quad = lane >> 4;

  const unsigned char* mu = (const unsigned char*)maskp + (size_t)l * (Sq * Sq);
  const int* mi = (const int*)maskp + (size_t)l * (Sq * Sq);
  int myok = 1;
  if (lane < Sq) myok = (mu[lane * (Sq + 1)] != 0) ? 1 : 0;
  const unsigned long long bal = __ballot(myok);
  const unsigned long long MM = (1ULL << Sq) - 1ULL;
  const int use_u8 = ((bal & MM) == MM) ? 1 : 0;

  const uint4 z4 = {0u, 0u, 0u, 0u};
  for (int t = lane; t < 576; t += 64) ((uint4*)VT)[t] = z4;
  for (int t = lane; t < 432; t += 64) ((uint4*)P)[t]  = z4;
  for (int t = lane; t < 264; t += 64) {
    const int j = t >> 3, ck = t & 7;
    const uint4 src = *(const uint4*)(V + hbase + (size_t)j * Dq + ck * 8);
    const u16* sp = (const u16*)&src;
#pragma unroll
    for (int e = 0; e < 8; e++) VT[(ck * 8 + e) * 72 + j] = sp[e];
  }
  __syncthreads();

  bf16x8 qf[3][2], kf[3][2];
#pragma unroll
  for (int m = 0; m < 3; m++) {
    const int rl = (m * 16 + r16 < Sq) ? (m * 16 + r16) : (Sq - 1);
#pragma unroll
    for (int kk = 0; kk < 2; kk++) {
      qf[m][kk] = *(const bf16x8*)(Q + hbase + (size_t)rl * Dq + kk * 32 + quad * 8);
      kf[m][kk] = *(const bf16x8*)(K + hbase + (size_t)rl * Dq + kk * 32 + quad * 8);
    }
  }
  f32x4 acc[3][3];
#pragma unroll
  for (int m = 0; m < 3; m++)
#pragma unroll
    for (int n = 0; n < 3; n++) acc[m][n] = (f32x4){0.f, 0.f, 0.f, 0.f};
#pragma unroll
  for (int kk = 0; kk < 2; kk++)
#pragma unroll
    for (int m = 0; m < 3; m++)
#pragma unroll
      for (int n = 0; n < 3; n++)
        acc[m][n] = __builtin_amdgcn_mfma_f32_16x16x32_bf16(qf[m][kk], kf[n][kk], acc[m][n], 0, 0, 0);

  float linv[3][4];
#pragma unroll
  for (int m = 0; m < 3; m++) {
    float v[3][4];
#pragma unroll
    for (int n = 0; n < 3; n++) {
      const int c = n * 16 + r16;
#pragma unroll
      for (int r = 0; r < 4; r++) {
        const int R = m * 16 + quad * 4 + r;
        float madd = -1e9f;
        if (R < Sq && c < Sq) {
          const int mv = use_u8 ? (int)mu[R * Sq + c] : mi[R * Sq + c];
          madd = mv ? 0.f : -1e9f;
        }
        v[n][r] = acc[m][n][r] * 0.125f + madd;
      }
    }
    float mr[4], sum[4];
#pragma unroll
    for (int r = 0; r < 4; r++) {
      mr[r] = fmaxf(fmaxf(v[0][r], v[1][r]), v[2][r]);
#pragma unroll
      for (int off = 8; off > 0; off >>= 1) mr[r] = fmaxf(mr[r], __shfl_xor(mr[r], off));
      sum[r] = 0.f;
    }
#pragma unroll
    for (int n = 0; n < 3; n++)
#pragma unroll
      for (int r = 0; r < 4; r++) { v[n][r] = __expf(v[n][r] - mr[r]); sum[r] += v[n][r]; }
#pragma unroll
    for (int r = 0; r < 4; r++) {
#pragma unroll
      for (int off = 8; off > 0; off >>= 1) sum[r] += __shfl_xor(sum[r], off);
      linv[m][r] = 1.0f / sum[r];
    }
#pragma unroll
    for (int n = 0; n < 3; n++)
#pragma unroll
      for (int r = 0; r < 4; r++)
        P[(m * 16 + quad * 4 + r) * 72 + n * 16 + r16] = f2bf(v[n][r]);
  }
  __syncthreads();

  bf16x8 pa[3][2], vb[4][2];
#pragma unroll
  for (int m = 0; m < 3; m++)
#pragma unroll
    for (int kk = 0; kk < 2; kk++)
      pa[m][kk] = *(const bf16x8*)(P + (m * 16 + r16) * 72 + kk * 32 + quad * 8);
#pragma unroll
  for (int n = 0; n < 4; n++)
#pragma unroll
    for (int kk = 0; kk < 2; kk++)
      vb[n][kk] = *(const bf16x8*)(VT + (n * 16 + r16) * 72 + kk * 32 + quad * 8);
  f32x4 o[3][4];
#pragma unroll
  for (int m = 0; m < 3; m++)
#pragma unroll
    for (int n = 0; n < 4; n++) o[m][n] = (f32x4){0.f, 0.f, 0.f, 0.f};
#pragma unroll
  for (int kk = 0; kk < 2; kk++)
#pragma unroll
    for (int m = 0; m < 3; m++)
#pragma unroll
      for (int n = 0; n < 4; n++)
        o[m][n] = __builtin_amdgcn_mfma_f32_16x16x32_bf16(pa[m][kk], vb[n][kk], o[m][n], 0, 0, 0);

#pragma unroll
  for (int m = 0; m < 3; m++)
#pragma unroll
    for (int r = 0; r < 4; r++) {
      const int i = m * 16 + quad * 4 + r;
      if (i < Sq) {
#pragma unroll
        for (int n = 0; n < 4; n++)
          O[hbase + (size_t)i * Dq + n * 16 + r16] = f2bf(o[m][n][r] * linv[m][r]);
      }
    }
}

// ---------------- head: LN(CLS) -> relu -> dot Wh + bh, one wave per sample
__global__ __launch_bounds__(256) void head_kernel(const float* __restrict__ X,
                                                   const float* __restrict__ hw, const float* __restrict__ hb,
                                                   const float* __restrict__ Wh, const float* __restrict__ bh,
                                                   float* __restrict__ out) {
  const int wave = threadIdx.x >> 6, lane = threadIdx.x & 63;
  const int b = blockIdx.x * 4 + wave;
  const float* xr = X + ((size_t)b * Sq + (Sq - 1)) * Dq + lane * 8;
  const float4 a  = *(const float4*)xr;
  const float4 bb = *(const float4*)(xr + 4);
  const float xv[8] = {a.x, a.y, a.z, a.w, bb.x, bb.y, bb.z, bb.w};
  float s = 0.f, ss = 0.f;
#pragma unroll
  for (int i = 0; i < 8; i++) { s += xv[i]; ss += xv[i] * xv[i]; }
#pragma unroll
  for (int off = 32; off > 0; off >>= 1) { s += __shfl_xor(s, off); ss += __shfl_xor(ss, off); }
  const float mean = s * (1.0f / Dq);
  const float rstd = rsqrtf(ss * (1.0f / Dq) - mean * mean + 1e-5f);
  float part = 0.f;
#pragma unroll
  for (int i = 0; i < 8; i++) {
    const float c = (xv[i] - mean) * rstd * hw[lane * 8 + i] + hb[lane * 8 + i];
    part += fmaxf(c, 0.f) * Wh[lane * 8 + i];
  }
#pragma unroll
  for (int off = 32; off > 0; off >>= 1) part += __shfl_xor(part, off);
  if (lane == 0) out[b] = part + bh[0];
}

extern "C" void kernel_launch(void* const* d_in, const int* in_sizes, int n_in,
                              void* d_out, int out_size, void* d_ws, size_t ws_size,
                              hipStream_t stream) {
  (void)in_sizes; (void)n_in; (void)out_size;
  const float* x_num   = (const float*)d_in[0];
  const int*   x_cat   = (const int*)d_in[1];
  const float* w_num   = (const float*)d_in[2];
  const float* b_num   = (const float*)d_in[3];
  const float* emb_cat = (const float*)d_in[4];
  const float* b_cat   = (const float*)d_in[5];
  const float* cls     = (const float*)d_in[6];
  const float* ln1_w   = (const float*)d_in[7];
  const float* ln1_b   = (const float*)d_in[8];
  const float* Wq      = (const float*)d_in[9];
  const float* bq      = (const float*)d_in[10];
  const float* Wk      = (const float*)d_in[11];
  const float* bk      = (const float*)d_in[12];
  const float* Wv      = (const float*)d_in[13];
  const float* bv      = (const float*)d_in[14];
  const float* Wo      = (const float*)d_in[15];
  const float* bo      = (const float*)d_in[16];
  const float* ln2_w   = (const float*)d_in[17];
  const float* ln2_b   = (const float*)d_in[18];
  const float* Wf1     = (const float*)d_in[19];
  const float* bf1     = (const float*)d_in[20];
  const float* Wf2     = (const float*)d_in[21];
  const float* bf2     = (const float*)d_in[22];
  const void*  mask    = d_in[23];
  const float* hln_w   = (const float*)d_in[25];
  const float* hln_b   = (const float*)d_in[26];
  const float* Wh      = (const float*)d_in[27];
  const float* bhp     = (const float*)d_in[28];
  float* out = (float*)d_out;

  const size_t WBYTES = 15728640ULL;
  int Bc = Bq;
  while (Bc > 128) {
    const size_t need = WBYTES + (size_t)Bc * Sq * 6144ULL;
    if (need <= ws_size) break;
    Bc >>= 1;
  }
  const size_t Mc = (size_t)Bc * Sq;

  char* ws = (char*)d_ws;
  u16* Wbase = (u16*)ws;
  float* X   = (float*)(ws + WBYTES);
  u16* Hb    = (u16*)((char*)X + Mc * 2048);
  u16* Qb    = (u16*)((char*)Hb + Mc * 1024);
  u16* Kb    = Qb + Mc * 512;
  u16* Vb    = Kb + Mc * 512;
  u16* AGb   = Qb;

  u16* WqT  = Wbase;
  u16* WkT  = WqT  + 786432;
  u16* WvT  = WkT  + 786432;
  u16* WoT  = WvT  + 786432;
  u16* Wf1T = WoT  + 786432;
  u16* Wf2T = Wf1T + 3145728;

  wconv_kernel<<<dim3(16, 16, 3), 256, 0, stream>>>(Wq, WqT, 512, 512);
  wconv_kernel<<<dim3(16, 16, 3), 256, 0, stream>>>(Wk, WkT, 512, 512);
  wconv_kernel<<<dim3(16, 16, 3), 256, 0, stream>>>(Wv, WvT, 512, 512);
  wconv_kernel<<<dim3(16, 16, 3), 256, 0, stream>>>(Wo, WoT, 512, 512);
  wconv_kernel<<<dim3(64, 16, 3), 256, 0, stream>>>(Wf1, Wf1T, 512, 2048);
  wconv_kernel<<<dim3(16, 32, 3), 256, 0, stream>>>(Wf2, Wf2T, 1024, 512);

  const int mb  = (int)(Mc / 128);   // 128-row blocks (gemm_kernel)
  const int mb64 = (int)(Mc / 64);   // 64-row blocks (gemm_ln_kernel)

  for (int c0 = 0; c0 < Bq; c0 += Bc) {
    tok_ln_kernel<<<(int)(Mc / 4), 256, 0, stream>>>(x_num, x_cat, w_num, b_num, emb_cat, b_cat, cls,
                                                     ln1_w, ln1_b, X, Hb, c0);

    for (int l = 0; l < Lq; l++) {
      gemm_kernel<0><<<dim3(mb, 4, 3), 256, 0, stream>>>(Hb,
          WqT + l * 262144, WkT + l * 262144, WvT + l * 262144,
          bq + l * 512, bk + l * 512, bv + l * 512,
          Qb, Kb, Vb, 512);
      attn_mfma_kernel<<<Bc * 2, 256, 0, stream>>>(Qb, Kb, Vb, mask, l, Hb);
      // Wo proj + residual + LN2 -> H (in-place A=Hb is safe: block-local rows)
      gemm_ln_kernel<<<mb64, 512, 0, stream>>>(Hb, WoT + l * 262144, bo + l * 512,
                                               ln2_w + l * 512, ln2_b + l * 512, X, Hb, 512);
      gemm_kernel<2><<<dim3(mb, 16, 1), 256, 0, stream>>>(Hb,
          Wf1T + l * 1048576, Wf1T + l * 1048576, Wf1T + l * 1048576,
          bf1 + l * 2048, bf1 + l * 2048, bf1 + l * 2048,
          AGb, AGb, AGb, 512);
      if (l < Lq - 1) {
        // FFN2 + residual + LN1(next layer) -> H
        gemm_ln_kernel<<<mb64, 512, 0, stream>>>(AGb, Wf2T + l * 524288, bf2 + l * 512,
                                                 ln1_w + (l + 1) * 512, ln1_b + (l + 1) * 512, X, Hb, 1024);
      } else {
        gemm_kernel<1><<<dim3(mb, 4, 1), 256, 0, stream>>>(AGb,
            Wf2T + l * 524288, Wf2T + l * 524288, Wf2T + l * 524288,
            bf2 + l * 512, bf2 + l * 512, bf2 + l * 512,
            X, X, X, 1024);
      }
    }
    head_kernel<<<Bc / 4, 256, 0, stream>>>(X, hln_w, hln_b, Wh, bhp, out + c0);
  }
}

// Round 5
// 2605.201 us; speedup vs baseline: 1.1287x; 1.1287x over previous
//
#include <hip/hip_runtime.h>
#include <stdint.h>

#define Bq    2048
#define NNq   24
#define NCq   8
#define CARDq 16
#define Dq    512
#define Hq    8
#define Lq    3
#define FHq   1024
#define Sq    33

typedef unsigned short u16;
typedef unsigned int   u32;
typedef __bf16 bf16x8 __attribute__((ext_vector_type(8)));
typedef float  f32x4  __attribute__((ext_vector_type(4)));

__device__ __forceinline__ u16 f2bf(float f) {
  u32 u = __builtin_bit_cast(u32, f);
  u = (u + 0x7fffu + ((u >> 16) & 1u)) >> 16;
  return (u16)u;
}
__device__ __forceinline__ float bf2f(u16 h) {
  u32 u = ((u32)h) << 16;
  return __builtin_bit_cast(float, u);
}

__device__ __forceinline__ void glds16(const void* g, void* l) {
  __builtin_amdgcn_global_load_lds((const __attribute__((address_space(1))) void*)g,
                                   (__attribute__((address_space(3))) void*)l, 16, 0, 0);
}

// ---------------- ALL weight transposes + f32->bf16 in ONE dispatch
// grid (2560, 3): per l, tiles 0-767 = Wq/Wk/Wv -> WqkvT[l][1536][512],
// 768-1023 = Wo, 1024-2047 = Wf1 (N=2048), 2048-2559 = Wf2 (K=1024).
__global__ __launch_bounds__(256) void wconv_all_kernel(const float* __restrict__ Wq,
                                                        const float* __restrict__ Wk,
                                                        const float* __restrict__ Wv,
                                                        const float* __restrict__ Wo,
                                                        const float* __restrict__ Wf1,
                                                        const float* __restrict__ Wf2,
                                                        u16* __restrict__ WqkvT,
                                                        u16* __restrict__ WoT,
                                                        u16* __restrict__ Wf1T,
                                                        u16* __restrict__ Wf2T) {
  __shared__ float tile[32][33];
  const int l = blockIdx.y;
  int id = blockIdx.x;
  const float* src; u16* dst; int K, N;
  if (id < 768) {
    const int m = id >> 8; id &= 255;
    src = ((m == 0) ? Wq : (m == 1) ? Wk : Wv) + (size_t)l * 262144;
    dst = WqkvT + (size_t)l * 786432 + (size_t)m * 262144;
    K = 512; N = 512;
  } else if (id < 1024) {
    id -= 768;
    src = Wo + (size_t)l * 262144;  dst = WoT + (size_t)l * 262144;
    K = 512; N = 512;
  } else if (id < 2048) {
    id -= 1024;
    src = Wf1 + (size_t)l * 1048576; dst = Wf1T + (size_t)l * 1048576;
    K = 512; N = 2048;
  } else {
    id -= 2048;
    src = Wf2 + (size_t)l * 524288;  dst = Wf2T + (size_t)l * 524288;
    K = 1024; N = 512;
  }
  const int ntn = N >> 5;
  const int n0 = (id % ntn) * 32, k0 = (id / ntn) * 32;
  const int tx = threadIdx.x & 31, ty = threadIdx.x >> 5;
#pragma unroll
  for (int r = 0; r < 32; r += 8)
    tile[ty + r][tx] = src[(size_t)(k0 + ty + r) * N + (n0 + tx)];
  __syncthreads();
#pragma unroll
  for (int r = 0; r < 32; r += 8)
    dst[(size_t)(n0 + ty + r) * K + (k0 + tx)] = f2bf(tile[tx][ty + r]);
}

// ---------------- fused tokenizer + LN1(layer0): one wave per token
__global__ __launch_bounds__(256) void tok_ln_kernel(const float* __restrict__ x_num,
                                                     const int* __restrict__ x_cat,
                                                     const float* __restrict__ w_num,
                                                     const float* __restrict__ b_num,
                                                     const float* __restrict__ emb_cat,
                                                     const float* __restrict__ b_cat,
                                                     const float* __restrict__ cls,
                                                     const float* __restrict__ gw,
                                                     const float* __restrict__ gb,
                                                     float* __restrict__ X,
                                                     u16* __restrict__ Hout, int c0) {
  const int wave = threadIdx.x >> 6, lane = threadIdx.x & 63;
  const int tok = blockIdx.x * 4 + wave;
  const int b   = tok / Sq;
  const int s   = tok - b * Sq;
  const int bg  = c0 + b;
  const int col0 = lane * 8;
  float v[8];
  if (s < NNq) {
    const float xv = x_num[bg * NNq + s];
    const float4 w0 = *(const float4*)(w_num + s * Dq + col0);
    const float4 w1 = *(const float4*)(w_num + s * Dq + col0 + 4);
    const float4 b0 = *(const float4*)(b_num + s * Dq + col0);
    const float4 b1 = *(const float4*)(b_num + s * Dq + col0 + 4);
    v[0]=fmaf(xv,w0.x,b0.x); v[1]=fmaf(xv,w0.y,b0.y); v[2]=fmaf(xv,w0.z,b0.z); v[3]=fmaf(xv,w0.w,b0.w);
    v[4]=fmaf(xv,w1.x,b1.x); v[5]=fmaf(xv,w1.y,b1.y); v[6]=fmaf(xv,w1.z,b1.z); v[7]=fmaf(xv,w1.w,b1.w);
  } else if (s < NNq + NCq) {
    const int j = s - NNq;
    const int row = x_cat[bg * NCq + j] + j * CARDq;
    const float4 e0 = *(const float4*)(emb_cat + (size_t)row * Dq + col0);
    const float4 e1 = *(const float4*)(emb_cat + (size_t)row * Dq + col0 + 4);
    const float4 b0 = *(const float4*)(b_cat + j * Dq + col0);
    const float4 b1 = *(const float4*)(b_cat + j * Dq + col0 + 4);
    v[0]=e0.x+b0.x; v[1]=e0.y+b0.y; v[2]=e0.z+b0.z; v[3]=e0.w+b0.w;
    v[4]=e1.x+b1.x; v[5]=e1.y+b1.y; v[6]=e1.z+b1.z; v[7]=e1.w+b1.w;
  } else {
    const float4 c0v = *(const float4*)(cls + col0);
    const float4 c1v = *(const float4*)(cls + col0 + 4);
    v[0]=c0v.x; v[1]=c0v.y; v[2]=c0v.z; v[3]=c0v.w;
    v[4]=c1v.x; v[5]=c1v.y; v[6]=c1v.z; v[7]=c1v.w;
  }
  float s1 = 0.f, s2 = 0.f;
#pragma unroll
  for (int i = 0; i < 8; i++) { s1 += v[i]; s2 += v[i] * v[i]; }
#pragma unroll
  for (int off = 32; off > 0; off >>= 1) { s1 += __shfl_xor(s1, off); s2 += __shfl_xor(s2, off); }
  const float mean = s1 * (1.0f / Dq);
  const float rstd = rsqrtf(s2 * (1.0f / Dq) - mean * mean + 1e-5f);
  float* xp = X + (size_t)tok * Dq + col0;
  *(float4*)xp       = (float4){v[0], v[1], v[2], v[3]};
  *(float4*)(xp + 4) = (float4){v[4], v[5], v[6], v[7]};
  const float* gwp = gw + col0;
  const float* gbp = gb + col0;
  u16 o[8];
#pragma unroll
  for (int i = 0; i < 8; i++) o[i] = f2bf((v[i] - mean) * rstd * gwp[i] + gbp[i]);
  uint4 pk;
  pk.x = (u32)o[0] | ((u32)o[1] << 16); pk.y = (u32)o[2] | ((u32)o[3] << 16);
  pk.z = (u32)o[4] | ((u32)o[5] << 16); pk.w = (u32)o[6] | ((u32)o[7] << 16);
  *(uint4*)(Hout + (size_t)tok * Dq + col0) = pk;
}

// ---------------- LayerNorm: X fp32 [Mc,512] -> H bf16 [Mc,512], one wave per row
__global__ __launch_bounds__(256) void ln_kernel(const float* __restrict__ X,
                                                 const float* __restrict__ gw,
                                                 const float* __restrict__ gb,
                                                 u16* __restrict__ Hout) {
  const int wave = threadIdx.x >> 6, lane = threadIdx.x & 63;
  const size_t row = (size_t)blockIdx.x * 4 + wave;
  const float* xr = X + row * Dq + lane * 8;
  const float4 a = *(const float4*)xr;
  const float4 b = *(const float4*)(xr + 4);
  float s  = a.x + a.y + a.z + a.w + b.x + b.y + b.z + b.w;
  float ss = a.x*a.x + a.y*a.y + a.z*a.z + a.w*a.w + b.x*b.x + b.y*b.y + b.z*b.z + b.w*b.w;
#pragma unroll
  for (int off = 32; off > 0; off >>= 1) { s += __shfl_xor(s, off); ss += __shfl_xor(ss, off); }
  const float mean = s * (1.0f / Dq);
  const float rstd = rsqrtf(ss * (1.0f / Dq) - mean * mean + 1e-5f);
  const float xv[8] = {a.x, a.y, a.z, a.w, b.x, b.y, b.z, b.w};
  const float* gwp = gw + lane * 8;
  const float* gbp = gb + lane * 8;
  u16 o[8];
#pragma unroll
  for (int i = 0; i < 8; i++) o[i] = f2bf((xv[i] - mean) * rstd * gwp[i] + gbp[i]);
  uint4 pk;
  pk.x = (u32)o[0] | ((u32)o[1] << 16); pk.y = (u32)o[2] | ((u32)o[3] << 16);
  pk.z = (u32)o[4] | ((u32)o[5] << 16); pk.w = (u32)o[6] | ((u32)o[7] << 16);
  *(uint4*)(Hout + row * Dq + lane * 8) = pk;
}

// ---------------- GEMM: C[M,N] = A[M,K] @ Bt[N,K]^T (+bias, mode-specific epilogue)
// MODE 1: X fp32 += acc + bias             (residual projections)
// MODE 2: AG = bf16((acc_a+ba)*relu(acc_g+bg))  (fused ReGLU FFN1)
// MODE 3: merged QKV: Bt = [Wq;Wk;Wv]^T [1536][512]; nblk>>2 selects output
//         buffer (stride ostride) and bias vector; out = bf16(acc + bias)
template <int MODE>
__global__ __launch_bounds__(256) void gemm_kernel(const u16* __restrict__ A,
                                                   const u16* __restrict__ Bt0, const u16* __restrict__ Bt1, const u16* __restrict__ Bt2,
                                                   const float* __restrict__ bi0, const float* __restrict__ bi1, const float* __restrict__ bi2,
                                                   void* __restrict__ out0, void* __restrict__ out1, void* __restrict__ out2,
                                                   size_t ostride, int K) {
  __shared__ uint4 smem4[1024];   // 16 KB
  char* smem = (char*)smem4;
  const int tid  = threadIdx.x;
  const int wave = tid >> 6;
  const int lane = tid & 63;
  const int mblk = blockIdx.x;
  const int nblk = blockIdx.y;
  const u16*   Bt;
  const float* bias;
  void*        outp;
  if (MODE == 3) {
    Bt = Bt0; bias = nullptr; outp = out0;
  } else {
    const int z = blockIdx.z;
    Bt   = (z == 0) ? Bt0 : (z == 1) ? Bt1 : Bt2;
    bias = (z == 0) ? bi0 : (z == 1) ? bi1 : bi2;
    outp = (z == 0) ? out0 : (z == 1) ? out1 : out2;
  }

  const int cg   = (lane & 3) ^ ((lane >> 3) & 3);
  const int arow = wave * 32 + (lane >> 2);
  const u16* gA0 = A + (size_t)(mblk * 128 + arow) * K + cg * 8;
  const u16* gA1 = gA0 + (size_t)16 * K;
  char* lA0 = smem + wave * 2048;
  char* lA1 = lA0 + 1024;

  const u16 *gB0, *gB1;
  char *lB0, *lB1;
  if (MODE == 2) {
    const int brow = wave * 16 + (lane >> 2);
    gB0 = Bt + (size_t)(nblk * 64 + brow) * K + cg * 8;
    gB1 = Bt + (size_t)(FHq + nblk * 64 + brow) * K + cg * 8;
    lB0 = smem + 8192  + wave * 1024;
    lB1 = smem + 12288 + wave * 1024;
  } else {
    const int brow = wave * 32 + (lane >> 2);
    gB0 = Bt + (size_t)(nblk * 128 + brow) * K + cg * 8;
    gB1 = gB0 + (size_t)16 * K;
    lB0 = smem + 8192 + wave * 2048;
    lB1 = lB0 + 1024;
  }

  const int slot = (lane >> 4) ^ ((lane >> 1) & 3);
  const int r16  = lane & 15;
  const int wm   = (wave >> 1) * 64;
  int aoff[4], boff[4];
#pragma unroll
  for (int i = 0; i < 4; i++) aoff[i] = (wm + i * 16 + r16) * 64 + slot * 16;
  if (MODE == 2) {
    const int wn = (wave & 1) * 32;
#pragma unroll
    for (int j = 0; j < 2; j++) {
      boff[j]     = 8192  + (wn + j * 16 + r16) * 64 + slot * 16;
      boff[2 + j] = 12288 + (wn + j * 16 + r16) * 64 + slot * 16;
    }
  } else {
    const int wn = (wave & 1) * 64;
#pragma unroll
    for (int j = 0; j < 4; j++) boff[j] = 8192 + (wn + j * 16 + r16) * 64 + slot * 16;
  }

  f32x4 acc[16];
#pragma unroll
  for (int i = 0; i < 16; i++) acc[i] = (f32x4){0.f, 0.f, 0.f, 0.f};

  const int kiter = K >> 5;
  for (int kk = 0; kk < kiter; kk++) {
    __syncthreads();
    glds16(gA0, lA0); glds16(gA1, lA1);
    glds16(gB0, lB0); glds16(gB1, lB1);
    gA0 += 32; gA1 += 32; gB0 += 32; gB1 += 32;
    __syncthreads();

    if (MODE == 2) {
      bf16x8 af[4], ba[2], bg[2];
#pragma unroll
      for (int i = 0; i < 4; i++) af[i] = *(const bf16x8*)(smem + aoff[i]);
#pragma unroll
      for (int j = 0; j < 2; j++) {
        ba[j] = *(const bf16x8*)(smem + boff[j]);
        bg[j] = *(const bf16x8*)(smem + boff[2 + j]);
      }
#pragma unroll
      for (int i = 0; i < 4; i++)
#pragma unroll
        for (int j = 0; j < 2; j++) {
          acc[i * 2 + j]     = __builtin_amdgcn_mfma_f32_16x16x32_bf16(af[i], ba[j], acc[i * 2 + j], 0, 0, 0);
          acc[8 + i * 2 + j] = __builtin_amdgcn_mfma_f32_16x16x32_bf16(af[i], bg[j], acc[8 + i * 2 + j], 0, 0, 0);
        }
    } else {
      bf16x8 af[4], bf[4];
#pragma unroll
      for (int i = 0; i < 4; i++) af[i] = *(const bf16x8*)(smem + aoff[i]);
#pragma unroll
      for (int j = 0; j < 4; j++) bf[j] = *(const bf16x8*)(smem + boff[j]);
#pragma unroll
      for (int i = 0; i < 4; i++)
#pragma unroll
        for (int j = 0; j < 4; j++)
          acc[i * 4 + j] = __builtin_amdgcn_mfma_f32_16x16x32_bf16(af[i], bf[j], acc[i * 4 + j], 0, 0, 0);
    }
  }

  const int quad = lane >> 4;
  if (MODE == 3) {
    const int buf = nblk >> 2;                     // 0=Q 1=K 2=V (uniform per block)
    u16* C = (u16*)out0 + (size_t)buf * ostride;
    const float* biasp = (buf == 0) ? bi0 : (buf == 1) ? bi1 : bi2;
    const int colbase = (nblk & 3) * 128 + (wave & 1) * 64;
#pragma unroll
    for (int j = 0; j < 4; j++) {
      const int c = colbase + j * 16 + r16;        // [0, 512)
      const float bv = biasp[c];
#pragma unroll
      for (int i = 0; i < 4; i++) {
        const int r0 = mblk * 128 + wm + i * 16 + quad * 4;
        f32x4 v = acc[i * 4 + j];
#pragma unroll
        for (int r = 0; r < 4; r++)
          C[(size_t)(r0 + r) * Dq + c] = f2bf(v[r] + bv);
      }
    }
  } else if (MODE == 1) {
    float* X = (float*)outp;
    const int wn = (wave & 1) * 64;
#pragma unroll
    for (int j = 0; j < 4; j++) {
      const int c = nblk * 128 + wn + j * 16 + r16;
      const float bv = bias[c];
#pragma unroll
      for (int i = 0; i < 4; i++) {
        const int r0 = mblk * 128 + wm + i * 16 + quad * 4;
        f32x4 v = acc[i * 4 + j];
#pragma unroll
        for (int r = 0; r < 4; r++) {
          const size_t idx = (size_t)(r0 + r) * Dq + c;
          X[idx] += v[r] + bv;
        }
      }
    }
  } else if (MODE == 2) {
    u16* AG = (u16*)outp;
    const int wn = (wave & 1) * 32;
#pragma unroll
    for (int j = 0; j < 2; j++) {
      const int c = nblk * 64 + wn + j * 16 + r16;
      const float bva = bias[c];
      const float bvg = bias[FHq + c];
#pragma unroll
      for (int i = 0; i < 4; i++) {
        const int r0 = mblk * 128 + wm + i * 16 + quad * 4;
        f32x4 va = acc[i * 2 + j];
        f32x4 vg = acc[8 + i * 2 + j];
#pragma unroll
        for (int r = 0; r < 4; r++) {
          const float av = va[r] + bva;
          const float gv = vg[r] + bvg;
          AG[(size_t)(r0 + r) * FHq + c] = f2bf(av * fmaxf(gv, 0.f));
        }
      }
    }
  }
}

// ---------------- MFMA sparse attention: 4 waves/block, 1 head per wave
__global__ __launch_bounds__(256) void attn_mfma_kernel(const u16* __restrict__ Q,
                                                        const u16* __restrict__ K,
                                                        const u16* __restrict__ V,
                                                        const void* __restrict__ maskp,
                                                        int l, u16* __restrict__ O) {
  __shared__ u16 lds_all[4][8064];
  const int wave = threadIdx.x >> 6, lane = threadIdx.x & 63;
  const int b = blockIdx.x >> 1;
  const int h = (blockIdx.x & 1) * 4 + wave;
  u16* VT = &lds_all[wave][0];
  u16* P  = &lds_all[wave][64 * 72];
  const size_t hbase = (size_t)b * (Sq * Dq) + (size_t)h * 64;
  const int r16 = lane & 15, quad = lane >> 4;

  const unsigned char* mu = (const unsigned char*)maskp + (size_t)l * (Sq * Sq);
  const int* mi = (const int*)maskp + (size_t)l * (Sq * Sq);
  int myok = 1;
  if (lane < Sq) myok = (mu[lane * (Sq + 1)] != 0) ? 1 : 0;
  const unsigned long long bal = __ballot(myok);
  const unsigned long long MM = (1ULL << Sq) - 1ULL;
  const int use_u8 = ((bal & MM) == MM) ? 1 : 0;

  const uint4 z4 = {0u, 0u, 0u, 0u};
  for (int t = lane; t < 576; t += 64) ((uint4*)VT)[t] = z4;
  for (int t = lane; t < 432; t += 64) ((uint4*)P)[t]  = z4;
  for (int t = lane; t < 264; t += 64) {
    const int j = t >> 3, ck = t & 7;
    const uint4 src = *(const uint4*)(V + hbase + (size_t)j * Dq + ck * 8);
    const u16* sp = (const u16*)&src;
#pragma unroll
    for (int e = 0; e < 8; e++) VT[(ck * 8 + e) * 72 + j] = sp[e];
  }
  __syncthreads();

  bf16x8 qf[3][2], kf[3][2];
#pragma unroll
  for (int m = 0; m < 3; m++) {
    const int rl = (m * 16 + r16 < Sq) ? (m * 16 + r16) : (Sq - 1);
#pragma unroll
    for (int kk = 0; kk < 2; kk++) {
      qf[m][kk] = *(const bf16x8*)(Q + hbase + (size_t)rl * Dq + kk * 32 + quad * 8);
      kf[m][kk] = *(const bf16x8*)(K + hbase + (size_t)rl * Dq + kk * 32 + quad * 8);
    }
  }
  f32x4 acc[3][3];
#pragma unroll
  for (int m = 0; m < 3; m++)
#pragma unroll
    for (int n = 0; n < 3; n++) acc[m][n] = (f32x4){0.f, 0.f, 0.f, 0.f};
#pragma unroll
  for (int kk = 0; kk < 2; kk++)
#pragma unroll
    for (int m = 0; m < 3; m++)
#pragma unroll
      for (int n = 0; n < 3; n++)
        acc[m][n] = __builtin_amdgcn_mfma_f32_16x16x32_bf16(qf[m][kk], kf[n][kk], acc[m][n], 0, 0, 0);

  float linv[3][4];
#pragma unroll
  for (int m = 0; m < 3; m++) {
    float v[3][4];
#pragma unroll
    for (int n = 0; n < 3; n++) {
      const int c = n * 16 + r16;
#pragma unroll
      for (int r = 0; r < 4; r++) {
        const int R = m * 16 + quad * 4 + r;
        float madd = -1e9f;
        if (R < Sq && c < Sq) {
          const int mv = use_u8 ? (int)mu[R * Sq + c] : mi[R * Sq + c];
          madd = mv ? 0.f : -1e9f;
        }
        v[n][r] = acc[m][n][r] * 0.125f + madd;
      }
    }
    float mr[4], sum[4];
#pragma unroll
    for (int r = 0; r < 4; r++) {
      mr[r] = fmaxf(fmaxf(v[0][r], v[1][r]), v[2][r]);
#pragma unroll
      for (int off = 8; off > 0; off >>= 1) mr[r] = fmaxf(mr[r], __shfl_xor(mr[r], off));
      sum[r] = 0.f;
    }
#pragma unroll
    for (int n = 0; n < 3; n++)
#pragma unroll
      for (int r = 0; r < 4; r++) { v[n][r] = __expf(v[n][r] - mr[r]); sum[r] += v[n][r]; }
#pragma unroll
    for (int r = 0; r < 4; r++) {
#pragma unroll
      for (int off = 8; off > 0; off >>= 1) sum[r] += __shfl_xor(sum[r], off);
      linv[m][r] = 1.0f / sum[r];
    }
#pragma unroll
    for (int n = 0; n < 3; n++)
#pragma unroll
      for (int r = 0; r < 4; r++)
        P[(m * 16 + quad * 4 + r) * 72 + n * 16 + r16] = f2bf(v[n][r]);
  }
  __syncthreads();

  bf16x8 pa[3][2], vb[4][2];
#pragma unroll
  for (int m = 0; m < 3; m++)
#pragma unroll
    for (int kk = 0; kk < 2; kk++)
      pa[m][kk] = *(const bf16x8*)(P + (m * 16 + r16) * 72 + kk * 32 + quad * 8);
#pragma unroll
  for (int n = 0; n < 4; n++)
#pragma unroll
    for (int kk = 0; kk < 2; kk++)
      vb[n][kk] = *(const bf16x8*)(VT + (n * 16 + r16) * 72 + kk * 32 + quad * 8);
  f32x4 o[3][4];
#pragma unroll
  for (int m = 0; m < 3; m++)
#pragma unroll
    for (int n = 0; n < 4; n++) o[m][n] = (f32x4){0.f, 0.f, 0.f, 0.f};
#pragma unroll
  for (int kk = 0; kk < 2; kk++)
#pragma unroll
    for (int m = 0; m < 3; m++)
#pragma unroll
      for (int n = 0; n < 4; n++)
        o[m][n] = __builtin_amdgcn_mfma_f32_16x16x32_bf16(pa[m][kk], vb[n][kk], o[m][n], 0, 0, 0);

#pragma unroll
  for (int m = 0; m < 3; m++)
#pragma unroll
    for (int r = 0; r < 4; r++) {
      const int i = m * 16 + quad * 4 + r;
      if (i < Sq) {
#pragma unroll
        for (int n = 0; n < 4; n++)
          O[hbase + (size_t)i * Dq + n * 16 + r16] = f2bf(o[m][n][r] * linv[m][r]);
      }
    }
}

// ---------------- head: LN(CLS) -> relu -> dot Wh + bh, one wave per sample
__global__ __launch_bounds__(256) void head_kernel(const float* __restrict__ X,
                                                   const float* __restrict__ hw, const float* __restrict__ hb,
                                                   const float* __restrict__ Wh, const float* __restrict__ bh,
                                                   float* __restrict__ out) {
  const int wave = threadIdx.x >> 6, lane = threadIdx.x & 63;
  const int b = blockIdx.x * 4 + wave;
  const float* xr = X + ((size_t)b * Sq + (Sq - 1)) * Dq + lane * 8;
  const float4 a  = *(const float4*)xr;
  const float4 bb = *(const float4*)(xr + 4);
  const float xv[8] = {a.x, a.y, a.z, a.w, bb.x, bb.y, bb.z, bb.w};
  float s = 0.f, ss = 0.f;
#pragma unroll
  for (int i = 0; i < 8; i++) { s += xv[i]; ss += xv[i] * xv[i]; }
#pragma unroll
  for (int off = 32; off > 0; off >>= 1) { s += __shfl_xor(s, off); ss += __shfl_xor(ss, off); }
  const float mean = s * (1.0f / Dq);
  const float rstd = rsqrtf(ss * (1.0f / Dq) - mean * mean + 1e-5f);
  float part = 0.f;
#pragma unroll
  for (int i = 0; i < 8; i++) {
    const float c = (xv[i] - mean) * rstd * hw[lane * 8 + i] + hb[lane * 8 + i];
    part += fmaxf(c, 0.f) * Wh[lane * 8 + i];
  }
#pragma unroll
  for (int off = 32; off > 0; off >>= 1) part += __shfl_xor(part, off);
  if (lane == 0) out[b] = part + bh[0];
}

extern "C" void kernel_launch(void* const* d_in, const int* in_sizes, int n_in,
                              void* d_out, int out_size, void* d_ws, size_t ws_size,
                              hipStream_t stream) {
  (void)in_sizes; (void)n_in; (void)out_size;
  const float* x_num   = (const float*)d_in[0];
  const int*   x_cat   = (const int*)d_in[1];
  const float* w_num   = (const float*)d_in[2];
  const float* b_num   = (const float*)d_in[3];
  const float* emb_cat = (const float*)d_in[4];
  const float* b_cat   = (const float*)d_in[5];
  const float* cls     = (const float*)d_in[6];
  const float* ln1_w   = (const float*)d_in[7];
  const float* ln1_b   = (const float*)d_in[8];
  const float* Wq      = (const float*)d_in[9];
  const float* bq      = (const float*)d_in[10];
  const float* Wk      = (const float*)d_in[11];
  const float* bk      = (const float*)d_in[12];
  const float* Wv      = (const float*)d_in[13];
  const float* bv      = (const float*)d_in[14];
  const float* Wo      = (const float*)d_in[15];
  const float* bo      = (const float*)d_in[16];
  const float* ln2_w   = (const float*)d_in[17];
  const float* ln2_b   = (const float*)d_in[18];
  const float* Wf1     = (const float*)d_in[19];
  const float* bf1     = (const float*)d_in[20];
  const float* Wf2     = (const float*)d_in[21];
  const float* bf2     = (const float*)d_in[22];
  const void*  mask    = d_in[23];
  const float* hln_w   = (const float*)d_in[25];
  const float* hln_b   = (const float*)d_in[26];
  const float* Wh      = (const float*)d_in[27];
  const float* bhp     = (const float*)d_in[28];
  float* out = (float*)d_out;

  const size_t WBYTES = 15728640ULL;
  int Bc = Bq;
  while (Bc > 128) {
    const size_t need = WBYTES + (size_t)Bc * Sq * 6144ULL;
    if (need <= ws_size) break;
    Bc >>= 1;
  }
  const size_t Mc = (size_t)Bc * Sq;

  char* ws = (char*)d_ws;
  u16* Wbase = (u16*)ws;
  float* X   = (float*)(ws + WBYTES);
  u16* Hb    = (u16*)((char*)X + Mc * 2048);
  u16* Qb    = (u16*)((char*)Hb + Mc * 1024);
  u16* Kb    = Qb + Mc * 512;
  u16* Vb    = Kb + Mc * 512;
  u16* AGb   = Qb;

  u16* WqkvT = Wbase;               // [L][1536][512]
  u16* WoT   = WqkvT + 2359296;     // [L][512][512]
  u16* Wf1T  = WoT   + 786432;      // [L][2048][512]
  u16* Wf2T  = Wf1T  + 3145728;     // [L][512][1024]

  wconv_all_kernel<<<dim3(2560, 3), 256, 0, stream>>>(Wq, Wk, Wv, Wo, Wf1, Wf2,
                                                      WqkvT, WoT, Wf1T, Wf2T);

  const int mb = (int)(Mc / 128);

  for (int c0 = 0; c0 < Bq; c0 += Bc) {
    tok_ln_kernel<<<(int)(Mc / 4), 256, 0, stream>>>(x_num, x_cat, w_num, b_num, emb_cat, b_cat, cls,
                                                     ln1_w, ln1_b, X, Hb, c0);

    for (int l = 0; l < Lq; l++) {
      // merged QKV: one dispatch, 12 N-blocks over [Wq;Wk;Wv]
      gemm_kernel<3><<<dim3(mb, 12, 1), 256, 0, stream>>>(Hb,
          WqkvT + l * 786432, nullptr, nullptr,
          bq + l * 512, bk + l * 512, bv + l * 512,
          Qb, nullptr, nullptr, Mc * 512, 512);
      attn_mfma_kernel<<<Bc * 2, 256, 0, stream>>>(Qb, Kb, Vb, mask, l, Hb);
      gemm_kernel<1><<<dim3(mb, 4, 1), 256, 0, stream>>>(Hb,
          WoT + l * 262144, WoT + l * 262144, WoT + l * 262144,
          bo + l * 512, bo + l * 512, bo + l * 512,
          X, X, X, 0, 512);
      ln_kernel<<<(int)(Mc / 4), 256, 0, stream>>>(X, ln2_w + l * 512, ln2_b + l * 512, Hb);
      gemm_kernel<2><<<dim3(mb, 16, 1), 256, 0, stream>>>(Hb,
          Wf1T + l * 1048576, Wf1T + l * 1048576, Wf1T + l * 1048576,
          bf1 + l * 2048, bf1 + l * 2048, bf1 + l * 2048,
          AGb, AGb, AGb, 0, 512);
      gemm_kernel<1><<<dim3(mb, 4, 1), 256, 0, stream>>>(AGb,
          Wf2T + l * 524288, Wf2T + l * 524288, Wf2T + l * 524288,
          bf2 + l * 512, bf2 + l * 512, bf2 + l * 512,
          X, X, X, 0, 1024);
      if (l < Lq - 1)
        ln_kernel<<<(int)(Mc / 4), 256, 0, stream>>>(X, ln1_w + (l + 1) * 512, ln1_b + (l + 1) * 512, Hb);
    }
    head_kernel<<<Bc / 4, 256, 0, stream>>>(X, hln_w, hln_b, Wh, bhp, out + c0);
  }
}